// Round 1
// baseline (2179.270 us; speedup 1.0000x reference)
//
#include <hip/hip_runtime.h>

// Block-diagonal linear + bias + ReLU on MI355X (gfx950), fp32.
// out[b,p,o] = relu(sum_k x[b,p,k] * W[p,k,o] + bias[p,o])
// B=16384, P=64, K=64, O=64.
//
// Strategy: one block = one part p + 256 batch rows. lane (tid&63) = o.
// W[p][:,lane] in 64 VGPRs per lane. x rows double-buffer-staged into LDS
// via global_load_lds (width 16); compute reads x via broadcast
// ds_read_b128 (all lanes same address -> conflict-free), 64 v_fmac_f32
// per row into 4 independent accumulator chains. Coalesced dword stores.

#define NPARTS 64
#define KDIM   64
#define ODIM   64
#define PK     4096              // P*K = row stride of x / out in floats
#define CHUNK  64                // rows per LDS buffer (64*64*4B = 16 KiB)
#define NCHUNKS 4                // chunks per block
#define ROWS_PER_BLOCK (CHUNK * NCHUNKS)   // 256 rows
#define NBLOCKGROUPS (16384 / ROWS_PER_BLOCK)  // 64

typedef __attribute__((address_space(1))) const unsigned int gl_u32;
typedef __attribute__((address_space(3))) unsigned int lds_u32;

__global__ __launch_bounds__(256, 4) void parts_linear_relu(
    const float* __restrict__ x, const float* __restrict__ W,
    const float* __restrict__ bias, float* __restrict__ out)
{
  __shared__ float xbuf[2][CHUNK * KDIM];   // 2 x 16 KiB

  const int tid  = threadIdx.x;
  const int lane = tid & 63;                // output channel o
  const int wave = tid >> 6;

  const int p  = blockIdx.x & 63;
  const int g  = blockIdx.x >> 6;
  const int b0 = g * ROWS_PER_BLOCK;

  // --- W[p][:, lane] into registers (64 VGPRs), coalesced 256B per k ---
  float w[KDIM];
  {
    const float* Wp = W + p * (KDIM * ODIM) + lane;
#pragma unroll
    for (int k = 0; k < KDIM; ++k) w[k] = Wp[k * ODIM];
  }
  const float bv = bias[p * ODIM + lane];

  // --- stage one 64-row chunk (16 KiB) into xbuf[buf] via global_load_lds ---
  // thread t covers 16B at (row = i*16 + t/16, col4 = t%16); LDS dest is
  // linear in t -> wave-uniform base + lane*16 as required.
  auto stage = [&](int buf, int browbase) {
    const float* src0 = x + (browbase + (tid >> 4)) * PK + p * KDIM + ((tid & 15) << 2);
    char* dst0 = (char*)(&xbuf[buf][0]) + tid * 16;
#pragma unroll
    for (int i = 0; i < 4; ++i) {
      __builtin_amdgcn_global_load_lds(
          (gl_u32*)(src0 + i * 16 * PK),
          (lds_u32*)(dst0 + i * 4096),
          16, 0, 0);
    }
  };

  stage(0, b0);

  for (int c = 0; c < NCHUNKS; ++c) {
    // barrier: compiler-emitted vmcnt(0) guarantees chunk c's loads landed
    __syncthreads();
    if (c + 1 < NCHUNKS) stage((c + 1) & 1, b0 + (c + 1) * CHUNK);

    const float* xb = &xbuf[c & 1][0];
    const int rowglob = b0 + c * CHUNK;

    // each wave computes 16 of the 64 rows in this chunk
#pragma unroll 2
    for (int rr = 0; rr < CHUNK / 4; ++rr) {
      const int r = wave * (CHUNK / 4) + rr;
      const float* xr = xb + r * KDIM;
      float a0 = 0.f, a1 = 0.f, a2 = 0.f, a3 = 0.f;
#pragma unroll
      for (int k4 = 0; k4 < KDIM / 4; ++k4) {
        const float4 xv = *reinterpret_cast<const float4*>(xr + (k4 << 2));
        a0 = fmaf(xv.x, w[4 * k4 + 0], a0);
        a1 = fmaf(xv.y, w[4 * k4 + 1], a1);
        a2 = fmaf(xv.z, w[4 * k4 + 2], a2);
        a3 = fmaf(xv.w, w[4 * k4 + 3], a3);
      }
      float v = (a0 + a1) + (a2 + a3) + bv;
      v = fmaxf(v, 0.0f);
      out[(rowglob + r) * PK + p * ODIM + lane] = v;
    }
  }
}

extern "C" void kernel_launch(void* const* d_in, const int* in_sizes, int n_in,
                              void* d_out, int out_size, void* d_ws, size_t ws_size,
                              hipStream_t stream) {
  const float* x    = (const float*)d_in[0];
  const float* W    = (const float*)d_in[1];
  const float* bias = (const float*)d_in[2];
  float* out        = (float*)d_out;

  // grid: 64 parts x 64 row-groups = 4096 blocks of 256 threads
  dim3 grid(NPARTS * NBLOCKGROUPS);
  parts_linear_relu<<<grid, 256, 0, stream>>>(x, W, bias, out);
}

// Round 3
// 1132.060 us; speedup vs baseline: 1.9250x; 1.9250x over previous
//
#include <hip/hip_runtime.h>

// Block-diagonal linear + bias + ReLU on MI355X (gfx950), fp32.
// out[b,p,o] = relu(sum_k x[b,p,k] * W[p,k,o] + bias[p,o])
// B=16384, P=64, K=64, O=64.
//
// Strategy: one block = one part p + 256 batch rows. lane (tid&63) = o.
// W[p][:,lane] in 64 VGPRs per lane. x rows double-buffer-staged into LDS
// via global_load_lds (width 16); compute reads x via broadcast
// ds_read_b128 (all lanes same address -> conflict-free), 64 v_fmac_f32
// per row into 4 independent accumulator chains. Coalesced dword stores.
//
// R1 lesson: __launch_bounds__(256,4) + unroll-2 row loop made the
// scheduler hoist 32 ds_read_b128 (128 VGPRs of x in flight); allocator
// spilled w[64] to scratch (VGPR_Count=64, 4.3GB scratch reads, 1900us).
// Fix: VGPR headroom (256,3) => 168-cap, and pin the row loop to
// unroll 1 so only one row's 16 float4 are live at a time.
// (R2 bench was an infra GPUAcquisitionTimeout — this is the same kernel
// resubmitted for measurement.)

#define NPARTS 64
#define KDIM   64
#define ODIM   64
#define PK     4096              // P*K = row stride of x / out in floats
#define CHUNK  64                // rows per LDS buffer (64*64*4B = 16 KiB)
#define NCHUNKS 4                // chunks per block
#define ROWS_PER_BLOCK (CHUNK * NCHUNKS)   // 256 rows
#define NBLOCKGROUPS (16384 / ROWS_PER_BLOCK)  // 64

typedef __attribute__((address_space(1))) const unsigned int gl_u32;
typedef __attribute__((address_space(3))) unsigned int lds_u32;

__global__ __launch_bounds__(256, 3) void parts_linear_relu(
    const float* __restrict__ x, const float* __restrict__ W,
    const float* __restrict__ bias, float* __restrict__ out)
{
  __shared__ float xbuf[2][CHUNK * KDIM];   // 2 x 16 KiB

  const int tid  = threadIdx.x;
  const int wave = tid >> 6;
  const int lane = tid & 63;                // output channel o

  const int p  = blockIdx.x & 63;
  const int g  = blockIdx.x >> 6;
  const int b0 = g * ROWS_PER_BLOCK;

  // --- W[p][:, lane] into registers (64 VGPRs), coalesced 256B per k ---
  float w[KDIM];
  {
    const float* Wp = W + p * (KDIM * ODIM) + lane;
#pragma unroll
    for (int k = 0; k < KDIM; ++k) w[k] = Wp[k * ODIM];
  }
  const float bv = bias[p * ODIM + lane];

  // --- stage one 64-row chunk (16 KiB) into xbuf[buf] via global_load_lds ---
  // thread t covers 16B at (row = i*16 + t/16, col4 = t%16); LDS dest is
  // linear in t -> wave-uniform base + lane*16 as required.
  auto stage = [&](int buf, int browbase) {
    const float* src0 = x + (browbase + (tid >> 4)) * PK + p * KDIM + ((tid & 15) << 2);
    char* dst0 = (char*)(&xbuf[buf][0]) + tid * 16;
#pragma unroll
    for (int i = 0; i < 4; ++i) {
      __builtin_amdgcn_global_load_lds(
          (gl_u32*)(src0 + i * 16 * PK),
          (lds_u32*)(dst0 + i * 4096),
          16, 0, 0);
    }
  };

  stage(0, b0);

  for (int c = 0; c < NCHUNKS; ++c) {
    // barrier: compiler-emitted vmcnt(0) guarantees chunk c's loads landed
    __syncthreads();
    if (c + 1 < NCHUNKS) stage((c + 1) & 1, b0 + (c + 1) * CHUNK);

    const float* xb = &xbuf[c & 1][0];
    const int rowglob = b0 + c * CHUNK;

    // each wave computes 16 of the 64 rows in this chunk.
    // unroll 1: keep only ONE row's x (16 float4) live -> no spill.
#pragma unroll 1
    for (int rr = 0; rr < CHUNK / 4; ++rr) {
      const int r = wave * (CHUNK / 4) + rr;
      const float* xr = xb + r * KDIM;
      float a0 = 0.f, a1 = 0.f, a2 = 0.f, a3 = 0.f;
#pragma unroll
      for (int k4 = 0; k4 < KDIM / 4; ++k4) {
        const float4 xv = *reinterpret_cast<const float4*>(xr + (k4 << 2));
        a0 = fmaf(xv.x, w[4 * k4 + 0], a0);
        a1 = fmaf(xv.y, w[4 * k4 + 1], a1);
        a2 = fmaf(xv.z, w[4 * k4 + 2], a2);
        a3 = fmaf(xv.w, w[4 * k4 + 3], a3);
      }
      float v = (a0 + a1) + (a2 + a3) + bv;
      v = fmaxf(v, 0.0f);
      out[(rowglob + r) * PK + p * ODIM + lane] = v;
    }
  }
}

extern "C" void kernel_launch(void* const* d_in, const int* in_sizes, int n_in,
                              void* d_out, int out_size, void* d_ws, size_t ws_size,
                              hipStream_t stream) {
  const float* x    = (const float*)d_in[0];
  const float* W    = (const float*)d_in[1];
  const float* bias = (const float*)d_in[2];
  float* out        = (float*)d_out;

  // grid: 64 parts x 64 row-groups = 4096 blocks of 256 threads
  dim3 grid(NPARTS * NBLOCKGROUPS);
  parts_linear_relu<<<grid, 256, 0, stream>>>(x, W, bias, out);
}

// Round 5
// 501.880 us; speedup vs baseline: 4.3422x; 2.2556x over previous
//
#include <hip/hip_runtime.h>

// Block-diagonal linear + bias + ReLU on MI355X (gfx950), fp32.
// out[b,p,o] = relu(sum_k x[b,p,k] * W[p,k,o] + bias[p,o])
// B=16384, P=64, K=64, O=64.
//
// R1/R3 lesson: holding W[p][:,lane] as a 64-float register array gets
// spilled by the allocator no matter the launch_bounds (VGPR_Count came
// back 64 then 84; excess HBM traffic matched spill arithmetic).
// R4 structure: K-OUTER blocking. Per k-quad, each lane holds only a
// 4-register W quad (read from LDS, stride-64-dword -> bank lane%32,
// 2-way = free) and 16 per-row accumulators. x is read as broadcast
// ds_read_b128 (all lanes same address, conflict-free). Live state
// ~40 VGPR, nothing loop-invariant-and-bulky -> no spill candidate.
//
// Per k4 step / wave: 4 ds_read_b32 (W) + 16 ds_read_b128 broadcast (x)
// + 64 v_fmac_f32  => LDS ~40 cyc < VALU 128 cyc. Kernel-wide FMA floor
// ~55us, HBM floor ~85us -> expect ~95-140us, memory-bound-ish.
// (R4 bench was an infra GPUAcquisitionTimeout — identical kernel
// resubmitted for measurement.)

#define KDIM   64
#define ODIM   64
#define PK     4096              // P*K = row stride of x / out in floats
#define CHUNK  64                // rows per LDS x-buffer (16 KiB)
#define NCHUNKS 4
#define ROWS_PER_BLOCK (CHUNK * NCHUNKS)       // 256
#define NBLOCKGROUPS (16384 / ROWS_PER_BLOCK)  // 64

typedef __attribute__((address_space(1))) const unsigned int gl_u32;
typedef __attribute__((address_space(3))) unsigned int lds_u32;

__global__ __launch_bounds__(256, 3) void parts_linear_relu(
    const float* __restrict__ x, const float* __restrict__ W,
    const float* __restrict__ bias, float* __restrict__ out)
{
  __shared__ float wbuf[KDIM * ODIM];       // 16 KiB, W[p] linear [k][o]
  __shared__ float xbuf[2][CHUNK * KDIM];   // 2 x 16 KiB

  const int tid  = threadIdx.x;
  const int wave = tid >> 6;
  const int lane = tid & 63;                // output channel o

  const int p  = blockIdx.x & 63;
  const int g  = blockIdx.x >> 6;
  const int b0 = g * ROWS_PER_BLOCK;

  // --- stage W[p] (16 KiB) linearly into LDS: 4 passes x 256 thr x 16B ---
  {
    const float* Wp = W + p * (KDIM * ODIM);
    char* dst0 = (char*)wbuf + tid * 16;
#pragma unroll
    for (int i = 0; i < 4; ++i) {
      __builtin_amdgcn_global_load_lds(
          (gl_u32*)(Wp + i * 1024 + tid * 4),
          (lds_u32*)(dst0 + i * 4096), 16, 0, 0);
    }
  }

  // --- stage one 64-row x chunk (16 KiB): linear dest, wave-uniform+lane*16
  auto stage = [&](int buf, int browbase) {
    const float* src0 = x + (browbase + (tid >> 4)) * PK + p * KDIM + ((tid & 15) << 2);
    char* dst0 = (char*)(&xbuf[buf][0]) + tid * 16;
#pragma unroll
    for (int i = 0; i < 4; ++i) {
      __builtin_amdgcn_global_load_lds(
          (gl_u32*)(src0 + i * 16 * PK),
          (lds_u32*)(dst0 + i * 4096), 16, 0, 0);
    }
  };

  stage(0, b0);

  const float bv = bias[p * ODIM + lane];

  for (int c = 0; c < NCHUNKS; ++c) {
    // barrier's vmcnt(0) drain guarantees W + chunk c landed
    __syncthreads();
    if (c + 1 < NCHUNKS) stage((c + 1) & 1, b0 + (c + 1) * CHUNK);

    // this wave's 16 rows of the chunk
    const float* xb = &xbuf[c & 1][wave * 16 * KDIM];

    float acc[16];
#pragma unroll
    for (int r = 0; r < 16; ++r) acc[r] = 0.f;

    // K-outer: hold only a 4-reg W quad at a time
#pragma unroll 1
    for (int k4 = 0; k4 < KDIM / 4; ++k4) {
      const float w0 = wbuf[(4 * k4 + 0) * ODIM + lane];
      const float w1 = wbuf[(4 * k4 + 1) * ODIM + lane];
      const float w2 = wbuf[(4 * k4 + 2) * ODIM + lane];
      const float w3 = wbuf[(4 * k4 + 3) * ODIM + lane];
      const float* xk = xb + 4 * k4;
#pragma unroll
      for (int r = 0; r < 16; ++r) {
        const float4 xq = *reinterpret_cast<const float4*>(xk + r * KDIM);
        acc[r] = fmaf(xq.x, w0, acc[r]);
        acc[r] = fmaf(xq.y, w1, acc[r]);
        acc[r] = fmaf(xq.z, w2, acc[r]);
        acc[r] = fmaf(xq.w, w3, acc[r]);
      }
    }

    const int rowglob = b0 + c * CHUNK + wave * 16;
#pragma unroll
    for (int r = 0; r < 16; ++r) {
      const float v = fmaxf(acc[r] + bv, 0.0f);
      out[(rowglob + r) * PK + p * ODIM + lane] = v;   // 256B coalesced
    }
  }
}

extern "C" void kernel_launch(void* const* d_in, const int* in_sizes, int n_in,
                              void* d_out, int out_size, void* d_ws, size_t ws_size,
                              hipStream_t stream) {
  const float* x    = (const float*)d_in[0];
  const float* W    = (const float*)d_in[1];
  const float* bias = (const float*)d_in[2];
  float* out        = (float*)d_out;

  // grid: 64 parts x 64 row-groups = 4096 blocks of 256 threads
  dim3 grid(64 * NBLOCKGROUPS);
  parts_linear_relu<<<grid, 256, 0, stream>>>(x, W, bias, out);
}